// Round 12
// baseline (699.658 us; speedup 1.0000x reference)
//
#include <hip/hip_runtime.h>

#define D_MODEL 2048
#define NHEADS 16
#define HDIM 128
#define HIDDEN_ 5461
#define HP2 5632
#define BATCH 2
#define SEQ 2048
#define MTOK 4096

typedef unsigned short u16;
typedef __attribute__((ext_vector_type(8))) short bf16x8;
typedef __attribute__((ext_vector_type(4))) float f32x4;
typedef __attribute__((ext_vector_type(4))) short s16x4;

__device__ __forceinline__ u16 f2b(float f) {
  union { float f; unsigned u; } v; v.f = f;
  return (u16)((v.u + 0x7FFFu + ((v.u >> 16) & 1u)) >> 16);
}
__device__ __forceinline__ float b2f(u16 u) {
  union { unsigned u; float f; } v; v.u = ((unsigned)u) << 16;
  return v.f;
}
__device__ __forceinline__ void gload16(const void* g, void* l) {
  __builtin_amdgcn_global_load_lds(
      (const __attribute__((address_space(1))) unsigned int*)g,
      (__attribute__((address_space(3))) unsigned int*)l, 16, 0, 0);
}

#define SB0() __builtin_amdgcn_sched_barrier(0)
#define BARRIER() do { SB0(); __builtin_amdgcn_s_barrier(); SB0(); } while (0)
#define LGKM0() do { asm volatile("s_waitcnt lgkmcnt(0)" ::: "memory"); SB0(); } while (0)

// ---------------- conversions ----------------
__global__ __launch_bounds__(256) void k_conv8(const float* __restrict__ src,
                                               u16* __restrict__ dst, int n8) {
  int stride = gridDim.x * 256;
  for (int i = blockIdx.x * 256 + threadIdx.x; i < n8; i += stride) {
    const float4* s = (const float4*)src + (size_t)i * 2;
    float4 a = s[0], b = s[1];
    bf16x8 o;
    o[0] = f2b(a.x); o[1] = f2b(a.y); o[2] = f2b(a.z); o[3] = f2b(a.w);
    o[4] = f2b(b.x); o[5] = f2b(b.y); o[6] = f2b(b.z); o[7] = f2b(b.w);
    ((bf16x8*)dst)[i] = o;
  }
}

__global__ __launch_bounds__(256) void k_conv3(const float* __restrict__ s0,
                                               const float* __restrict__ s1,
                                               const float* __restrict__ s2,
                                               u16* __restrict__ dst) {
  const int n8 = D_MODEL * D_MODEL / 8;  // 2^19
  int total = 3 * n8;
  int stride = gridDim.x * 256;
  for (int i = blockIdx.x * 256 + threadIdx.x; i < total; i += stride) {
    int seg = i >> 19, j = i & (n8 - 1);
    const float* s = (seg == 0) ? s0 : (seg == 1 ? s1 : s2);
    const float4* sp = (const float4*)s + (size_t)j * 2;
    float4 a = sp[0], b = sp[1];
    bf16x8 o;
    o[0] = f2b(a.x); o[1] = f2b(a.y); o[2] = f2b(a.z); o[3] = f2b(a.w);
    o[4] = f2b(b.x); o[5] = f2b(b.y); o[6] = f2b(b.z); o[7] = f2b(b.w);
    ((bf16x8*)dst)[i] = o;
  }
}

// W13 fragment-interleaved conversion: frag nf even -> w1, odd -> w3 (same cols).
__global__ __launch_bounds__(256) void k_convw13(const float* __restrict__ w1,
                                                 const float* __restrict__ w3,
                                                 u16* __restrict__ dst) {
  const int n8 = (11264 * D_MODEL) / 8;
  int stride = gridDim.x * 256;
  for (int i = blockIdx.x * 256 + threadIdx.x; i < n8; i += stride) {
    int r = i >> 8, c8 = i & 255;
    int g = r >> 8, rem = r & 255;
    int wcb = rem >> 6, t = rem & 63, pp = t >> 4, ll = t & 15;
    int srow = g * 128 + wcb * 32 + (pp >> 1) * 16 + ll;
    bf16x8 o;
    if (srow < HIDDEN_) {
      const float* s = (pp & 1) ? w3 : w1;
      const float4* sp = (const float4*)(s + (size_t)srow * D_MODEL + c8 * 8);
      float4 a = sp[0], b = sp[1];
      o[0] = f2b(a.x); o[1] = f2b(a.y); o[2] = f2b(a.z); o[3] = f2b(a.w);
      o[4] = f2b(b.x); o[5] = f2b(b.y); o[6] = f2b(b.z); o[7] = f2b(b.w);
    } else {
      o = (bf16x8){0, 0, 0, 0, 0, 0, 0, 0};
    }
    ((bf16x8*)dst)[i] = o;
  }
}

__global__ __launch_bounds__(256) void k_convpad(const float* __restrict__ src,
                                                 u16* __restrict__ dst,
                                                 int srows, int scols, int drows, int dcols) {
  size_t n = (size_t)drows * dcols;
  size_t stride = (size_t)gridDim.x * 256;
  for (size_t i = blockIdx.x * 256 + threadIdx.x; i < n; i += stride) {
    int r = (int)(i / dcols), c = (int)(i % dcols);
    float v = (r < srows && c < scols) ? src[(size_t)r * scols + c] : 0.f;
    dst[i] = f2b(v);
  }
}

// ---------------- rmsnorm (fp32 in, bf16 out) ----------------
__global__ __launch_bounds__(256) void k_rmsnorm(const float* __restrict__ X,
                                                 const float* __restrict__ G,
                                                 u16* __restrict__ Out) {
  int row = blockIdx.x;
  int tid = threadIdx.x;
  const float4* x4 = (const float4*)(X + (size_t)row * D_MODEL);
  float4 a = x4[tid * 2], b = x4[tid * 2 + 1];
  float ss = a.x * a.x + a.y * a.y + a.z * a.z + a.w * a.w +
             b.x * b.x + b.y * b.y + b.z * b.z + b.w * b.w;
#pragma unroll
  for (int off = 1; off < 64; off <<= 1) ss += __shfl_xor(ss, off);
  __shared__ float part[4];
  if ((tid & 63) == 0) part[tid >> 6] = ss;
  __syncthreads();
  float rstd = rsqrtf((part[0] + part[1] + part[2] + part[3]) * (1.0f / D_MODEL) + 1e-6f);
  const float4* g4 = (const float4*)G;
  float4 ga = g4[tid * 2], gb = g4[tid * 2 + 1];
  bf16x8 o;
  o[0] = f2b(a.x * rstd * ga.x); o[1] = f2b(a.y * rstd * ga.y);
  o[2] = f2b(a.z * rstd * ga.z); o[3] = f2b(a.w * rstd * ga.w);
  o[4] = f2b(b.x * rstd * gb.x); o[5] = f2b(b.y * rstd * gb.y);
  o[6] = f2b(b.z * rstd * gb.z); o[7] = f2b(b.w * rstd * gb.w);
  *((bf16x8*)(Out + (size_t)row * D_MODEL) + tid) = o;
}

// ================= 256x(BN) 8-phase GEMM, LDS bank-swizzled (R11 winner) =================
// EPI: 0 bf16 | 1 qkv split | 2 f32+bias+res | 3 f32+res | 6 W13 reg-fused silu
template <int WN, int EPI>
__global__ __launch_bounds__(512, 2) void k_gemm2(const u16* __restrict__ A,
                                                  const u16* __restrict__ Bw,
                                                  const u16* __restrict__ Bw2,
                                                  void* __restrict__ O0,
                                                  void* __restrict__ O1,
                                                  void* __restrict__ O2,
                                                  const float* __restrict__ bias,
                                                  const float* __restrict__ res,
                                                  const u16* __restrict__ aux,
                                                  int M, int N, int K) {
  constexpr int BN = WN * 64;
  constexpr int PB = BN * 64;  // B plane bytes
  __shared__ __align__(128) char lds[65536 + 4 * PB];
  const int tid = threadIdx.x;
  const int w = tid >> 6, lane = tid & 63;
  const int lo = lane & 15, hi = lane >> 4;
  const int wr = w >> 2, wc = w & 3;

  const int ntN = N / BN;
  const int nwg = gridDim.x * gridDim.y;
  const int flat = blockIdx.y * gridDim.x + blockIdx.x;
  const int swz = (flat & 7) * (nwg >> 3) + (flat >> 3);
  const int tm = swz / ntN, tn = swz % ntN;
  const int m0 = tm * 256, n0 = tn * BN;

  const u16* bbase = Bw + (size_t)n0 * K;
  (void)Bw2;

  const int sslot = ((tid & 3) ^ ((tid >> 3) & 3)) * 8;  // pre-swizzled source slot

  auto stA = [&](int nb, int kk, int k0) {
#pragma unroll
    for (int j = 0; j < 2; ++j) {
      int row = j * 128 + (tid >> 2);
      const u16* g = A + (size_t)(m0 + row) * K + k0 + kk * 32 + sslot;
      gload16(g, lds + nb * 32768 + kk * 16384 + j * 8192 + tid * 16);
    }
  };
  auto stB = [&](int nb, int kk, int k0) {
#pragma unroll
    for (int j = 0; j < WN / 2; ++j) {
      int row = j * 128 + (tid >> 2);
      const u16* g = bbase + (size_t)row * K + k0 + kk * 32 + sslot;
      gload16(g, lds + 65536 + nb * 2 * PB + kk * PB + j * 8192 + tid * 16);
    }
  };
  auto ldA = [&](int buf, int kk, int mf) {
    int row = wr * 128 + mf * 16 + lo;
    int sl = hi ^ ((row >> 1) & 3);
    return *(const bf16x8*)(lds + buf * 32768 + kk * 16384 + row * 64 + sl * 16);
  };
  auto ldB = [&](int buf, int kk, int nf) {
    int row = wc * (WN * 16) + nf * 16 + lo;
    int sl = hi ^ ((row >> 1) & 3);
    return *(const bf16x8*)(lds + 65536 + buf * 2 * PB + kk * PB + row * 64 + sl * 16);
  };
#define VMCNT_CONFIRM()                                             \
  do {                                                              \
    if constexpr (WN == 4)                                          \
      asm volatile("s_waitcnt vmcnt(4)" ::: "memory");              \
    else                                                            \
      asm volatile("s_waitcnt vmcnt(3)" ::: "memory");              \
    SB0();                                                          \
  } while (0)

  f32x4 acc[8][WN];
#pragma unroll
  for (int i = 0; i < 8; i++)
#pragma unroll
    for (int j = 0; j < WN; j++) acc[i][j] = (f32x4){0.f, 0.f, 0.f, 0.f};

  stA(0, 0, 0);
  stB(0, 0, 0);
  stA(0, 1, 0);
  stB(0, 1, 0);
  VMCNT_CONFIRM();
  BARRIER();

  const int KT = K / 64;
  for (int kt = 0; kt < KT; ++kt) {
    const int buf = kt & 1, nb = buf ^ 1;
    int kn = (kt + 1) * 64;
    if (kn >= K) kn = 0;  // dummy stage on last tile (never consumed)
    bf16x8 aF[4], bF[WN];

    // ---- phase 1: kk=0, m-frags 0..3 ----
#pragma unroll
    for (int i = 0; i < 4; i++) aF[i] = ldA(buf, 0, i);
#pragma unroll
    for (int j = 0; j < WN; j++) bF[j] = ldB(buf, 0, j);
    stA(nb, 0, kn);
    BARRIER();
    LGKM0();
    __builtin_amdgcn_s_setprio(1);
#pragma unroll
    for (int i = 0; i < 4; i++)
#pragma unroll
      for (int j = 0; j < WN; j++)
        acc[i][j] = __builtin_amdgcn_mfma_f32_16x16x32_bf16(aF[i], bF[j], acc[i][j], 0, 0, 0);
    __builtin_amdgcn_s_setprio(0);
    BARRIER();

    // ---- phase 2: kk=0, m-frags 4..7 ----
#pragma unroll
    for (int i = 0; i < 4; i++) aF[i] = ldA(buf, 0, 4 + i);
    stB(nb, 0, kn);
    VMCNT_CONFIRM();
    BARRIER();
    LGKM0();
    __builtin_amdgcn_s_setprio(1);
#pragma unroll
    for (int i = 0; i < 4; i++)
#pragma unroll
      for (int j = 0; j < WN; j++)
        acc[4 + i][j] = __builtin_amdgcn_mfma_f32_16x16x32_bf16(aF[i], bF[j], acc[4 + i][j], 0, 0, 0);
    __builtin_amdgcn_s_setprio(0);
    BARRIER();

    // ---- phase 3: kk=1, m-frags 0..3 ----
#pragma unroll
    for (int i = 0; i < 4; i++) aF[i] = ldA(buf, 1, i);
#pragma unroll
    for (int j = 0; j < WN; j++) bF[j] = ldB(buf, 1, j);
    stA(nb, 1, kn);
    BARRIER();
    LGKM0();
    __builtin_amdgcn_s_setprio(1);
#pragma unroll
    for (int i = 0; i < 4; i++)
#pragma unroll
      for (int j = 0; j < WN; j++)
        acc[i][j] = __builtin_amdgcn_mfma_f32_16x16x32_bf16(aF[i], bF[j], acc[i][j], 0, 0, 0);
    __builtin_amdgcn_s_setprio(0);
    BARRIER();

    // ---- phase 4: kk=1, m-frags 4..7 ----
#pragma unroll
    for (int i = 0; i < 4; i++) aF[i] = ldA(buf, 1, 4 + i);
    stB(nb, 1, kn);
    VMCNT_CONFIRM();
    BARRIER();
    LGKM0();
    __builtin_amdgcn_s_setprio(1);
#pragma unroll
    for (int i = 0; i < 4; i++)
#pragma unroll
      for (int j = 0; j < WN; j++)
        acc[4 + i][j] = __builtin_amdgcn_mfma_f32_16x16x32_bf16(aF[i], bF[j], acc[4 + i][j], 0, 0, 0);
    __builtin_amdgcn_s_setprio(0);
    BARRIER();
  }

  // ---- epilogue ----
  if (EPI == 6) {
    int c0 = n0 >> 1;
#pragma unroll
    for (int i = 0; i < 8; i++) {
#pragma unroll
      for (int jp = 0; jp < WN; jp += 2) {
        int colL = wc * 32 + (jp >> 1) * 16 + lo;
#pragma unroll
        for (int r = 0; r < 4; r++) {
          int row = m0 + wr * 128 + i * 16 + hi * 4 + r;
          float v1 = acc[i][jp][r];
          float v3 = acc[i][jp + 1][r];
          float sig = 1.f / (1.f + __expf(-v1));
          ((u16*)O0)[(size_t)row * 5632 + c0 + colL] = f2b(v1 * sig * v3);
        }
      }
    }
    return;
  }
  u16* qkvout = nullptr;
  int c0 = 0;
  if (EPI == 1) {
    int seg = n0 >> 11;
    qkvout = (u16*)(seg == 0 ? O0 : (seg == 1 ? O1 : O2));
    c0 = n0 & 2047;
  }
#pragma unroll
  for (int i = 0; i < 8; i++) {
#pragma unroll
    for (int j = 0; j < WN; j++) {
      int colL = wc * (WN * 16) + j * 16 + lo;
#pragma unroll
      for (int r = 0; r < 4; r++) {
        int row = m0 + wr * 128 + i * 16 + hi * 4 + r;
        float v = acc[i][j][r];
        if (EPI == 0) {
          ((u16*)O0)[(size_t)row * N + n0 + colL] = f2b(v);
        } else if (EPI == 1) {
          qkvout[(size_t)row * 2048 + c0 + colL] = f2b(v);
        } else if (EPI == 2) {
          size_t idx = (size_t)row * N + n0 + colL;
          ((float*)O0)[idx] = v + bias[n0 + colL] + res[idx];
        } else if (EPI == 3) {
          size_t idx = (size_t)row * N + n0 + colL;
          ((float*)O0)[idx] = v + res[idx];
        }
      }
    }
  }
#undef VMCNT_CONFIRM
}

// ---------------- RoPE (in-place on bf16 q,k) ----------------
__global__ __launch_bounds__(256) void k_rope(u16* __restrict__ Qb, u16* __restrict__ Kb,
                                              const float* __restrict__ F) {
  int n = MTOK * (D_MODEL / 2);
  int stride = gridDim.x * 256;
  for (int t = blockIdx.x * 256 + threadIdx.x; t < n; t += stride) {
    int i = t & 63;
    int rest = t >> 6;
    int hh = rest & 15;
    int tok = rest >> 4;
    int s = tok & (SEQ - 1);
    float4 f = ((const float4*)F)[s * 64 + i];
    size_t off = (size_t)tok * D_MODEL + hh * HDIM + i * 2;
    float x0 = b2f(Qb[off]), x1 = b2f(Qb[off + 1]);
    Qb[off] = f2b(x0 * f.x + x1 * f.y);
    Qb[off + 1] = f2b(x0 * f.z + x1 * f.w);
    x0 = b2f(Kb[off]); x1 = b2f(Kb[off + 1]);
    Kb[off] = f2b(x0 * f.x + x1 * f.y);
    Kb[off + 1] = f2b(x0 * f.z + x1 * f.w);
  }
}

// ---------------- V transpose: V[4096tok][2048] -> VT[32bh][128d][2048s] ----------------
__global__ __launch_bounds__(256) void k_vt(const u16* __restrict__ V, u16* __restrict__ VT) {
  __shared__ u16 t[64][72];
  const int stile = blockIdx.x;
  const int bh = blockIdx.y;
  const int dz = blockIdx.z;
  const int b = bh >> 4, h = bh & 15;
  const int tok0 = b * SEQ + stile * 64;
  const int d0 = dz * 64;
  const int tid = threadIdx.x;
#pragma unroll
  for (int p = 0; p < 2; p++) {
    int idx = p * 256 + tid;
    int row = idx >> 3, seg = idx & 7;
    bf16x8 v = *(const bf16x8*)(V + (size_t)(tok0 + row) * D_MODEL + h * HDIM + d0 + seg * 8);
    *(bf16x8*)(&t[row][seg * 8]) = v;
  }
  __syncthreads();
#pragma unroll
  for (int p = 0; p < 2; p++) {
    int idx = p * 256 + tid;
    int dr = idx >> 3, seg = idx & 7;
    bf16x8 o;
#pragma unroll
    for (int e = 0; e < 8; e++) o[e] = t[seg * 8 + e][dr];
    *(bf16x8*)(VT + ((size_t)bh * HDIM + d0 + dr) * SEQ + stile * 64 + seg * 8) = o;
  }
}

// ---------------- flash v6: qg-shared P buffer -> LDS 37.4 KB -> 4 blocks/CU ----
// Same as R11's flash4 except Pl is shared across qg with per-qg lgkm fences
// (write -> lgkm0 -> read aP[qg] -> lgkm0 before next qg overwrites). Pl is
// per-wave so no barrier is needed; pattern correctness-validated in R6 flash5.
__global__ __launch_bounds__(256) void k_flash6(const u16* __restrict__ Q,
                                                const u16* __restrict__ Kb,
                                                const u16* __restrict__ VT,
                                                u16* __restrict__ O) {
  __shared__ u16 Kt[64 * 128];     // [key][d], slot^=(key&7)
  __shared__ u16 Vt[128 * 64];     // [d][k],  slot^=(d&7)
  __shared__ u16 Pl[4][16 * 72];   // per-wave, SHARED across qg
  const int tid = threadIdx.x;
  const int w = tid >> 6, lane = tid & 63;
  const int lo = lane & 15, hi = lane >> 4;
  const int qt = blockIdx.x, bh = blockIdx.y;
  const int b = bh >> 4, h = bh & 15;
  const size_t qrow0 = (size_t)b * SEQ + qt * 128 + w * 32;
  const float SC = 0.08838834764831845f * 1.4426950408889634f;  // scale * log2(e)

  bf16x8 aQ[2][4];
#pragma unroll
  for (int qg = 0; qg < 2; qg++)
#pragma unroll
    for (int kb = 0; kb < 4; kb++)
      aQ[qg][kb] = *(const bf16x8*)(Q + (qrow0 + qg * 16 + lo) * D_MODEL + h * HDIM + kb * 32 + hi * 8);

  float m_s[2] = {-3.0e38f, -3.0e38f}, l_s[2] = {0.f, 0.f};
  f32x4 oacc[2][8];
#pragma unroll
  for (int qg = 0; qg < 2; qg++)
#pragma unroll
    for (int d = 0; d < 8; d++) oacc[qg][d] = (f32x4){0.f, 0.f, 0.f, 0.f};

  const int krowL = tid >> 4;
  const int kslot = (tid & 15) ^ (krowL & 7);
  const int vrowL = tid >> 3;
  const int vslot = (tid & 7) ^ (vrowL & 7);
  const u16* Kbase = Kb + (size_t)b * SEQ * D_MODEL + h * HDIM;
  const u16* Vbase = VT + (size_t)bh * HDIM * SEQ;
  unsigned* Plw = (unsigned*)&Pl[w][0];  // u32 view

  bf16x8 kreg[4], vreg[4];
  auto issue = [&](int kt) {
#pragma unroll
    for (int t = 0; t < 4; t++) {
      int row = t * 16 + krowL;
      kreg[t] = *(const bf16x8*)(Kbase + (size_t)(kt * 64 + row) * D_MODEL + kslot * 8);
    }
#pragma unroll
    for (int t = 0; t < 4; t++) {
      int row = t * 32 + vrowL;
      vreg[t] = *(const bf16x8*)(Vbase + (size_t)row * SEQ + kt * 64 + vslot * 8);
    }
  };
  auto commit = [&]() {
#pragma unroll
    for (int t = 0; t < 4; t++)
      *(bf16x8*)((char*)Kt + t * 4096 + tid * 16) = kreg[t];
#pragma unroll
    for (int t = 0; t < 4; t++)
      *(bf16x8*)((char*)Vt + t * 4096 + tid * 16) = vreg[t];
  };

  // prologue: tile 0 into LDS
  issue(0);
  commit();
  BARRIER();

  const int NT = SEQ / 64;
  for (int kt = 0; kt < NT; kt++) {
    if (kt + 1 < NT) {
      issue(kt + 1);  // long-latency loads hide under this iteration's compute
      SB0();
    }

    // ---- QK^T (swapped): S^T[key][q] ----
    f32x4 sf[2][4];
#pragma unroll
    for (int cb = 0; cb < 4; cb++) {
      bf16x8 kA[4];
#pragma unroll
      for (int kb = 0; kb < 4; kb++) {
        int ps = (kb * 4 + hi) ^ (lo & 7);
        kA[kb] = *(const bf16x8*)(Kt + (cb * 16 + lo) * 128 + ps * 8);
      }
#pragma unroll
      for (int qg = 0; qg < 2; qg++) {
        f32x4 s = (f32x4){0.f, 0.f, 0.f, 0.f};
#pragma unroll
        for (int kb = 0; kb < 4; kb++)
          s = __builtin_amdgcn_mfma_f32_16x16x32_bf16(kA[kb], aQ[qg][kb], s, 0, 0, 0);
        sf[qg][cb] = s;
      }
    }

    // ---- softmax: lane-local over 16 keys + 2 wide shfls; defer-max ----
    float tsc[2];
    bool ok = true;
#pragma unroll
    for (int qg = 0; qg < 2; qg++) {
      float t0 = fmaxf(fmaxf(sf[qg][0][0], sf[qg][0][1]), fmaxf(sf[qg][0][2], sf[qg][0][3]));
      float t1 = fmaxf(fmaxf(sf[qg][1][0], sf[qg][1][1]), fmaxf(sf[qg][1][2], sf[qg][1][3]));
      float t2 = fmaxf(fmaxf(sf[qg][2][0], sf[qg][2][1]), fmaxf(sf[qg][2][2], sf[qg][2][3]));
      float t3 = fmaxf(fmaxf(sf[qg][3][0], sf[qg][3][1]), fmaxf(sf[qg][3][2], sf[qg][3][3]));
      float t = fmaxf(fmaxf(t0, t1), fmaxf(t2, t3));
      t = fmaxf(t, __shfl_xor(t, 16));
      t = fmaxf(t, __shfl_xor(t, 32));
      tsc[qg] = t * SC;
      ok = ok && (tsc[qg] - m_s[qg] <= 11.5f);
    }
    bool skip = __all(ok);

    bf16x8 aP[2][2];
#pragma unroll
    for (int qg = 0; qg < 2; qg++) {
      float mm = m_s[qg];
      if (!skip) {
        mm = fmaxf(m_s[qg], tsc[qg]);
        float alpha = exp2f(m_s[qg] - mm);
        l_s[qg] *= alpha;
#pragma unroll
        for (int d = 0; d < 8; d++) oacc[qg][d] *= alpha;
        m_s[qg] = mm;
      }
      float rs = 0.f;
#pragma unroll
      for (int cb = 0; cb < 4; cb++) {
        float p0 = exp2f(sf[qg][cb][0] * SC - mm);
        float p1 = exp2f(sf[qg][cb][1] * SC - mm);
        float p2 = exp2f(sf[qg][cb][2] * SC - mm);
        float p3 = exp2f(sf[qg][cb][3] * SC - mm);
        rs += (p0 + p1) + (p2 + p3);
        unsigned pk0, pk1;
        asm("v_cvt_pk_bf16_f32 %0, %1, %2" : "=v"(pk0) : "v"(p0), "v"(p1));
        asm("v_cvt_pk_bf16_f32 %0, %1, %2" : "=v"(pk1) : "v"(p2), "v"(p3));
        Plw[lo * 36 + cb * 8 + hi * 2 + 0] = pk0;
        Plw[lo * 36 + cb * 8 + hi * 2 + 1] = pk1;
      }
      rs += __shfl_xor(rs, 16);
      rs += __shfl_xor(rs, 32);
      l_s[qg] += rs;
      LGKM0();  // this qg's writes complete before its reads
      aP[qg][0] = *(const bf16x8*)(&Pl[w][lo * 72 + 0 * 32 + hi * 8]);
      aP[qg][1] = *(const bf16x8*)(&Pl[w][lo * 72 + 1 * 32 + hi * 8]);
      LGKM0();  // reads complete before next qg overwrites the shared buffer
    }

    // ---- PV (swapped): O^T[d][q] ----
#pragma unroll
    for (int db = 0; db < 8; db++) {
      bf16x8 vA[2];
#pragma unroll
      for (int ks = 0; ks < 2; ks++) {
        int ps = (ks * 4 + hi) ^ (lo & 7);
        vA[ks] = *(const bf16x8*)(Vt + (db * 16 + lo) * 64 + ps * 8);
      }
#pragma unroll
      for (int qg = 0; qg < 2; qg++)
#pragma unroll
        for (int ks = 0; ks < 2; ks++)
          oacc[qg][db] = __builtin_amdgcn_mfma_f32_16x16x32_bf16(vA[ks], aP[qg][ks], oacc[qg][db], 0, 0, 0);
    }

    if (kt + 1 < NT) {
      BARRIER();   // all waves done reading tile kt
      commit();    // implicit vmcnt waits only on our own loads (already landed)
      BARRIER();   // tile kt+1 visible
    }
  }

  // ---- epilogue: O^T[d][q] -> O[q][d], 8B packed stores ----
#pragma unroll
  for (int qg = 0; qg < 2; qg++) {
    float inv = 1.f / l_s[qg];
    size_t rowoff = (qrow0 + qg * 16 + lo) * D_MODEL + h * HDIM;
#pragma unroll
    for (int db = 0; db < 8; db++) {
      s16x4 o;
#pragma unroll
      for (int r = 0; r < 4; r++) o[r] = (short)f2b(oacc[qg][db][r] * inv);
      *(s16x4*)(O + rowoff + db * 16 + hi * 4) = o;
    }
  }
}

extern "C" void kernel_launch(void* const* d_in, const int* in_sizes, int n_in,
                              void* d_out, int out_size, void* d_ws, size_t ws_size,
                              hipStream_t stream) {
  (void)in_sizes; (void)n_in; (void)out_size; (void)ws_size;
  const float* x  = (const float*)d_in[0];
  const float* fc = (const float*)d_in[1];
  const float* wq = (const float*)d_in[2];
  const float* wk = (const float*)d_in[3];
  const float* wv = (const float*)d_in[4];
  const float* wo = (const float*)d_in[5];
  const float* bo = (const float*)d_in[6];
  const float* w1 = (const float*)d_in[7];
  const float* w3 = (const float*)d_in[8];
  const float* w2 = (const float*)d_in[9];
  const float* ga = (const float*)d_in[10];
  const float* gf = (const float*)d_in[11];
  float* out = (float*)d_out;  // also holds hres (fp32) between sublayers

  // ---- workspace (~185 MB) ----
  char* p = (char*)d_ws;
  auto alloc = [&](size_t bytes) { char* r = p; p += (bytes + 255) & ~(size_t)255; return r; };
  u16* xn   = (u16*)alloc((size_t)MTOK * D_MODEL * 2);  // A: reused as vbt
  u16* qb   = (u16*)alloc((size_t)MTOK * D_MODEL * 2);  // B: reused as hn
  u16* kb   = (u16*)alloc((size_t)MTOK * D_MODEL * 2);  // C
  u16* vb   = (u16*)alloc((size_t)MTOK * D_MODEL * 2);  // D: reused as ob
  u16* x1   = (u16*)alloc((size_t)MTOK * HP2 * 2);      // E
  u16* w13i = (u16*)alloc((size_t)11264 * D_MODEL * 2); // F: interleaved W1/W3 weights
  u16* wsl  = (u16*)alloc((size_t)3 * D_MODEL * D_MODEL * 2);  // G: shared weight slot
  u16* vbt = xn;
  u16* ob  = vb;
  u16* hn  = qb;

  // ---- attention sublayer ----
  k_rmsnorm<<<MTOK, 256, 0, stream>>>(x, ga, xn);
  k_conv3<<<1536, 256, 0, stream>>>(wq, wk, wv, wsl);
  k_gemm2<4, 1><<<dim3(6144 / 256, MTOK / 256), 512, 0, stream>>>(
      xn, wsl, nullptr, qb, kb, vb, nullptr, nullptr, nullptr, MTOK, 6144, D_MODEL);
  k_rope<<<1024, 256, 0, stream>>>(qb, kb, fc);
  k_vt<<<dim3(SEQ / 64, BATCH * NHEADS, 2), 256, 0, stream>>>(vb, vbt);
  dim3 gfl(SEQ / 128, BATCH * NHEADS);
  k_flash6<<<gfl, 256, 0, stream>>>(qb, kb, vbt, ob);  // ob overwrites vb (dead after k_vt)
  k_conv8<<<1024, 256, 0, stream>>>(wo, wsl, D_MODEL * D_MODEL / 8);
  k_gemm2<2, 2><<<dim3(2048 / 128, MTOK / 256), 512, 0, stream>>>(
      ob, wsl, nullptr, out, nullptr, nullptr, bo, x, nullptr, MTOK, D_MODEL, D_MODEL);

  // ---- FFN sublayer (hres lives in `out`) ----
  k_rmsnorm<<<MTOK, 256, 0, stream>>>(out, gf, hn);  // hn overwrites qb (dead)
  k_convw13<<<2048, 256, 0, stream>>>(w1, w3, w13i);
  // W13 fused: N = 11264 fragment-interleaved; epilogue = reg-only silu(x1)*x3 -> x1
  k_gemm2<4, 6><<<dim3(11264 / 256, MTOK / 256), 512, 0, stream>>>(
      hn, w13i, nullptr, x1, nullptr, nullptr, nullptr, nullptr, nullptr, MTOK, 11264, D_MODEL);
  k_convpad<<<1024, 256, 0, stream>>>(w2, wsl, D_MODEL, HIDDEN_, D_MODEL, HP2);
  k_gemm2<2, 3><<<dim3(2048 / 128, MTOK / 256), 512, 0, stream>>>(
      x1, wsl, nullptr, out, nullptr, nullptr, nullptr, out, nullptr, MTOK, D_MODEL, HP2);
}

// Round 13
// 687.895 us; speedup vs baseline: 1.0171x; 1.0171x over previous
//
#include <hip/hip_runtime.h>

#define D_MODEL 2048
#define NHEADS 16
#define HDIM 128
#define HIDDEN_ 5461
#define HP2 5632
#define BATCH 2
#define SEQ 2048
#define MTOK 4096

typedef unsigned short u16;
typedef __attribute__((ext_vector_type(8))) short bf16x8;
typedef __attribute__((ext_vector_type(4))) float f32x4;
typedef __attribute__((ext_vector_type(4))) short s16x4;

__device__ __forceinline__ u16 f2b(float f) {
  union { float f; unsigned u; } v; v.f = f;
  return (u16)((v.u + 0x7FFFu + ((v.u >> 16) & 1u)) >> 16);
}
__device__ __forceinline__ float b2f(u16 u) {
  union { unsigned u; float f; } v; v.u = ((unsigned)u) << 16;
  return v.f;
}
__device__ __forceinline__ void gload16(const void* g, void* l) {
  __builtin_amdgcn_global_load_lds(
      (const __attribute__((address_space(1))) unsigned int*)g,
      (__attribute__((address_space(3))) unsigned int*)l, 16, 0, 0);
}

#define SB0() __builtin_amdgcn_sched_barrier(0)
#define BARRIER() do { SB0(); __builtin_amdgcn_s_barrier(); SB0(); } while (0)
#define LGKM0() do { asm volatile("s_waitcnt lgkmcnt(0)" ::: "memory"); SB0(); } while (0)

// ---------------- conversions ----------------
__global__ __launch_bounds__(256) void k_conv8(const float* __restrict__ src,
                                               u16* __restrict__ dst, int n8) {
  int stride = gridDim.x * 256;
  for (int i = blockIdx.x * 256 + threadIdx.x; i < n8; i += stride) {
    const float4* s = (const float4*)src + (size_t)i * 2;
    float4 a = s[0], b = s[1];
    bf16x8 o;
    o[0] = f2b(a.x); o[1] = f2b(a.y); o[2] = f2b(a.z); o[3] = f2b(a.w);
    o[4] = f2b(b.x); o[5] = f2b(b.y); o[6] = f2b(b.z); o[7] = f2b(b.w);
    ((bf16x8*)dst)[i] = o;
  }
}

__global__ __launch_bounds__(256) void k_conv3(const float* __restrict__ s0,
                                               const float* __restrict__ s1,
                                               const float* __restrict__ s2,
                                               u16* __restrict__ dst) {
  const int n8 = D_MODEL * D_MODEL / 8;  // 2^19
  int total = 3 * n8;
  int stride = gridDim.x * 256;
  for (int i = blockIdx.x * 256 + threadIdx.x; i < total; i += stride) {
    int seg = i >> 19, j = i & (n8 - 1);
    const float* s = (seg == 0) ? s0 : (seg == 1 ? s1 : s2);
    const float4* sp = (const float4*)s + (size_t)j * 2;
    float4 a = sp[0], b = sp[1];
    bf16x8 o;
    o[0] = f2b(a.x); o[1] = f2b(a.y); o[2] = f2b(a.z); o[3] = f2b(a.w);
    o[4] = f2b(b.x); o[5] = f2b(b.y); o[6] = f2b(b.z); o[7] = f2b(b.w);
    ((bf16x8*)dst)[i] = o;
  }
}

// W13 fragment-interleaved conversion: frag nf even -> w1, odd -> w3 (same cols).
__global__ __launch_bounds__(256) void k_convw13(const float* __restrict__ w1,
                                                 const float* __restrict__ w3,
                                                 u16* __restrict__ dst) {
  const int n8 = (11264 * D_MODEL) / 8;
  int stride = gridDim.x * 256;
  for (int i = blockIdx.x * 256 + threadIdx.x; i < n8; i += stride) {
    int r = i >> 8, c8 = i & 255;
    int g = r >> 8, rem = r & 255;
    int wcb = rem >> 6, t = rem & 63, pp = t >> 4, ll = t & 15;
    int srow = g * 128 + wcb * 32 + (pp >> 1) * 16 + ll;
    bf16x8 o;
    if (srow < HIDDEN_) {
      const float* s = (pp & 1) ? w3 : w1;
      const float4* sp = (const float4*)(s + (size_t)srow * D_MODEL + c8 * 8);
      float4 a = sp[0], b = sp[1];
      o[0] = f2b(a.x); o[1] = f2b(a.y); o[2] = f2b(a.z); o[3] = f2b(a.w);
      o[4] = f2b(b.x); o[5] = f2b(b.y); o[6] = f2b(b.z); o[7] = f2b(b.w);
    } else {
      o = (bf16x8){0, 0, 0, 0, 0, 0, 0, 0};
    }
    ((bf16x8*)dst)[i] = o;
  }
}

// w2 [2048][5461] fp32 -> dst [2048][5632] bf16 (K-pad). Compile-time dims so the
// index math is magic-mul, vectorized 16B stores.
__global__ __launch_bounds__(256) void k_convw2(const float* __restrict__ src,
                                                u16* __restrict__ dst) {
  const int n8 = 2048 * (HP2 / 8);  // 2048 * 704
  int stride = gridDim.x * 256;
  for (int i = blockIdx.x * 256 + threadIdx.x; i < n8; i += stride) {
    int r = i / 704, c8 = i % 704;
    int c = c8 * 8;
    const float* s = src + (size_t)r * HIDDEN_ + c;
    bf16x8 o;
#pragma unroll
    for (int e = 0; e < 8; e++) o[e] = (c + e < HIDDEN_) ? f2b(s[e]) : (u16)0;
    ((bf16x8*)dst)[i] = o;
  }
}

// ---------------- rmsnorm (fp32 in, bf16 out) ----------------
__global__ __launch_bounds__(256) void k_rmsnorm(const float* __restrict__ X,
                                                 const float* __restrict__ G,
                                                 u16* __restrict__ Out) {
  int row = blockIdx.x;
  int tid = threadIdx.x;
  const float4* x4 = (const float4*)(X + (size_t)row * D_MODEL);
  float4 a = x4[tid * 2], b = x4[tid * 2 + 1];
  float ss = a.x * a.x + a.y * a.y + a.z * a.z + a.w * a.w +
             b.x * b.x + b.y * b.y + b.z * b.z + b.w * b.w;
#pragma unroll
  for (int off = 1; off < 64; off <<= 1) ss += __shfl_xor(ss, off);
  __shared__ float part[4];
  if ((tid & 63) == 0) part[tid >> 6] = ss;
  __syncthreads();
  float rstd = rsqrtf((part[0] + part[1] + part[2] + part[3]) * (1.0f / D_MODEL) + 1e-6f);
  const float4* g4 = (const float4*)G;
  float4 ga = g4[tid * 2], gb = g4[tid * 2 + 1];
  bf16x8 o;
  o[0] = f2b(a.x * rstd * ga.x); o[1] = f2b(a.y * rstd * ga.y);
  o[2] = f2b(a.z * rstd * ga.z); o[3] = f2b(a.w * rstd * ga.w);
  o[4] = f2b(b.x * rstd * gb.x); o[5] = f2b(b.y * rstd * gb.y);
  o[6] = f2b(b.z * rstd * gb.z); o[7] = f2b(b.w * rstd * gb.w);
  *((bf16x8*)(Out + (size_t)row * D_MODEL) + tid) = o;
}

// ================= 256x(BN) 8-phase GEMM, LDS bank-swizzled =================
// EPI: 0 bf16 | 1 qkv split (V written TRANSPOSED to O2=[bh][d][s]) |
//      2 f32+bias+res | 3 f32+res | 6 W13 reg-fused silu
template <int WN, int EPI>
__global__ __launch_bounds__(512, 2) void k_gemm2(const u16* __restrict__ A,
                                                  const u16* __restrict__ Bw,
                                                  const u16* __restrict__ Bw2,
                                                  void* __restrict__ O0,
                                                  void* __restrict__ O1,
                                                  void* __restrict__ O2,
                                                  const float* __restrict__ bias,
                                                  const float* __restrict__ res,
                                                  const u16* __restrict__ aux,
                                                  int M, int N, int K) {
  constexpr int BN = WN * 64;
  constexpr int PB = BN * 64;  // B plane bytes
  __shared__ __align__(128) char lds[65536 + 4 * PB];
  const int tid = threadIdx.x;
  const int w = tid >> 6, lane = tid & 63;
  const int lo = lane & 15, hi = lane >> 4;
  const int wr = w >> 2, wc = w & 3;

  const int ntN = N / BN;
  const int nwg = gridDim.x * gridDim.y;
  const int flat = blockIdx.y * gridDim.x + blockIdx.x;
  const int swz = (flat & 7) * (nwg >> 3) + (flat >> 3);
  const int tm = swz / ntN, tn = swz % ntN;
  const int m0 = tm * 256, n0 = tn * BN;

  const u16* bbase = Bw + (size_t)n0 * K;
  (void)Bw2;

  const int sslot = ((tid & 3) ^ ((tid >> 3) & 3)) * 8;  // pre-swizzled source slot

  auto stA = [&](int nb, int kk, int k0) {
#pragma unroll
    for (int j = 0; j < 2; ++j) {
      int row = j * 128 + (tid >> 2);
      const u16* g = A + (size_t)(m0 + row) * K + k0 + kk * 32 + sslot;
      gload16(g, lds + nb * 32768 + kk * 16384 + j * 8192 + tid * 16);
    }
  };
  auto stB = [&](int nb, int kk, int k0) {
#pragma unroll
    for (int j = 0; j < WN / 2; ++j) {
      int row = j * 128 + (tid >> 2);
      const u16* g = bbase + (size_t)row * K + k0 + kk * 32 + sslot;
      gload16(g, lds + 65536 + nb * 2 * PB + kk * PB + j * 8192 + tid * 16);
    }
  };
  auto ldA = [&](int buf, int kk, int mf) {
    int row = wr * 128 + mf * 16 + lo;
    int sl = hi ^ ((row >> 1) & 3);
    return *(const bf16x8*)(lds + buf * 32768 + kk * 16384 + row * 64 + sl * 16);
  };
  auto ldB = [&](int buf, int kk, int nf) {
    int row = wc * (WN * 16) + nf * 16 + lo;
    int sl = hi ^ ((row >> 1) & 3);
    return *(const bf16x8*)(lds + 65536 + buf * 2 * PB + kk * PB + row * 64 + sl * 16);
  };
#define VMCNT_CONFIRM()                                             \
  do {                                                              \
    if constexpr (WN == 4)                                          \
      asm volatile("s_waitcnt vmcnt(4)" ::: "memory");              \
    else                                                            \
      asm volatile("s_waitcnt vmcnt(3)" ::: "memory");              \
    SB0();                                                          \
  } while (0)

  f32x4 acc[8][WN];
#pragma unroll
  for (int i = 0; i < 8; i++)
#pragma unroll
    for (int j = 0; j < WN; j++) acc[i][j] = (f32x4){0.f, 0.f, 0.f, 0.f};

  stA(0, 0, 0);
  stB(0, 0, 0);
  stA(0, 1, 0);
  stB(0, 1, 0);
  VMCNT_CONFIRM();
  BARRIER();

  const int KT = K / 64;
  for (int kt = 0; kt < KT; ++kt) {
    const int buf = kt & 1, nb = buf ^ 1;
    int kn = (kt + 1) * 64;
    if (kn >= K) kn = 0;  // dummy stage on last tile (never consumed)
    bf16x8 aF[4], bF[WN];

    // ---- phase 1: kk=0, m-frags 0..3 ----
#pragma unroll
    for (int i = 0; i < 4; i++) aF[i] = ldA(buf, 0, i);
#pragma unroll
    for (int j = 0; j < WN; j++) bF[j] = ldB(buf, 0, j);
    stA(nb, 0, kn);
    BARRIER();
    LGKM0();
    __builtin_amdgcn_s_setprio(1);
#pragma unroll
    for (int i = 0; i < 4; i++)
#pragma unroll
      for (int j = 0; j < WN; j++)
        acc[i][j] = __builtin_amdgcn_mfma_f32_16x16x32_bf16(aF[i], bF[j], acc[i][j], 0, 0, 0);
    __builtin_amdgcn_s_setprio(0);
    BARRIER();

    // ---- phase 2: kk=0, m-frags 4..7 ----
#pragma unroll
    for (int i = 0; i < 4; i++) aF[i] = ldA(buf, 0, 4 + i);
    stB(nb, 0, kn);
    VMCNT_CONFIRM();
    BARRIER();
    LGKM0();
    __builtin_amdgcn_s_setprio(1);
#pragma unroll
    for (int i = 0; i < 4; i++)
#pragma unroll
      for (int j = 0; j < WN; j++)
        acc[4 + i][j] = __builtin_amdgcn_mfma_f32_16x16x32_bf16(aF[i], bF[j], acc[4 + i][j], 0, 0, 0);
    __builtin_amdgcn_s_setprio(0);
    BARRIER();

    // ---- phase 3: kk=1, m-frags 0..3 ----
#pragma unroll
    for (int i = 0; i < 4; i++) aF[i] = ldA(buf, 1, i);
#pragma unroll
    for (int j = 0; j < WN; j++) bF[j] = ldB(buf, 1, j);
    stA(nb, 1, kn);
    BARRIER();
    LGKM0();
    __builtin_amdgcn_s_setprio(1);
#pragma unroll
    for (int i = 0; i < 4; i++)
#pragma unroll
      for (int j = 0; j < WN; j++)
        acc[i][j] = __builtin_amdgcn_mfma_f32_16x16x32_bf16(aF[i], bF[j], acc[i][j], 0, 0, 0);
    __builtin_amdgcn_s_setprio(0);
    BARRIER();

    // ---- phase 4: kk=1, m-frags 4..7 ----
#pragma unroll
    for (int i = 0; i < 4; i++) aF[i] = ldA(buf, 1, 4 + i);
    stB(nb, 1, kn);
    VMCNT_CONFIRM();
    BARRIER();
    LGKM0();
    __builtin_amdgcn_s_setprio(1);
#pragma unroll
    for (int i = 0; i < 4; i++)
#pragma unroll
      for (int j = 0; j < WN; j++)
        acc[4 + i][j] = __builtin_amdgcn_mfma_f32_16x16x32_bf16(aF[i], bF[j], acc[4 + i][j], 0, 0, 0);
    __builtin_amdgcn_s_setprio(0);
    BARRIER();
  }

  // ---- epilogue ----
  if (EPI == 6) {
    int c0 = n0 >> 1;
#pragma unroll
    for (int i = 0; i < 8; i++) {
#pragma unroll
      for (int jp = 0; jp < WN; jp += 2) {
        int colL = wc * 32 + (jp >> 1) * 16 + lo;
#pragma unroll
        for (int r = 0; r < 4; r++) {
          int row = m0 + wr * 128 + i * 16 + hi * 4 + r;
          float v1 = acc[i][jp][r];
          float v3 = acc[i][jp + 1][r];
          float sig = 1.f / (1.f + __expf(-v1));
          ((u16*)O0)[(size_t)row * 5632 + c0 + colL] = f2b(v1 * sig * v3);
        }
      }
    }
    return;
  }
  if (EPI == 1) {
    int seg = n0 >> 11;
    int c0 = n0 & 2047;
    if (seg < 2) {
      u16* qkvout = (u16*)(seg == 0 ? O0 : O1);
#pragma unroll
      for (int i = 0; i < 8; i++)
#pragma unroll
        for (int j = 0; j < WN; j++) {
          int colL = wc * (WN * 16) + j * 16 + lo;
#pragma unroll
          for (int r = 0; r < 4; r++) {
            int row = m0 + wr * 128 + i * 16 + hi * 4 + r;
            qkvout[(size_t)row * 2048 + c0 + colL] = f2b(acc[i][j][r]);
          }
        }
    } else {
      // V written transposed: vt[((b*16+h)*128 + d) * 2048 + s], s-packed 8B stores
      u16* vt = (u16*)O2;
      int b = m0 >> 11;
      int sb = m0 & 2047;
#pragma unroll
      for (int i = 0; i < 8; i++)
#pragma unroll
        for (int j = 0; j < WN; j++) {
          int col = c0 + wc * (WN * 16) + j * 16 + lo;
          size_t base = ((size_t)(b * 16 + (col >> 7)) * 128 + (col & 127)) * 2048;
          int s0 = sb + wr * 128 + i * 16 + hi * 4;
          s16x4 o;
#pragma unroll
          for (int r = 0; r < 4; r++) o[r] = (short)f2b(acc[i][j][r]);
          *(s16x4*)(vt + base + s0) = o;
        }
    }
    return;
  }
#pragma unroll
  for (int i = 0; i < 8; i++) {
#pragma unroll
    for (int j = 0; j < WN; j++) {
      int colL = wc * (WN * 16) + j * 16 + lo;
#pragma unroll
      for (int r = 0; r < 4; r++) {
        int row = m0 + wr * 128 + i * 16 + hi * 4 + r;
        float v = acc[i][j][r];
        if (EPI == 0) {
          ((u16*)O0)[(size_t)row * N + n0 + colL] = f2b(v);
        } else if (EPI == 2) {
          size_t idx = (size_t)row * N + n0 + colL;
          ((float*)O0)[idx] = v + bias[n0 + colL] + res[idx];
        } else if (EPI == 3) {
          size_t idx = (size_t)row * N + n0 + colL;
          ((float*)O0)[idx] = v + res[idx];
        }
      }
    }
  }
#undef VMCNT_CONFIRM
}

// ---------------- RoPE (in-place on bf16 q,k) ----------------
__global__ __launch_bounds__(256) void k_rope(u16* __restrict__ Qb, u16* __restrict__ Kb,
                                              const float* __restrict__ F) {
  int n = MTOK * (D_MODEL / 2);
  int stride = gridDim.x * 256;
  for (int t = blockIdx.x * 256 + threadIdx.x; t < n; t += stride) {
    int i = t & 63;
    int rest = t >> 6;
    int hh = rest & 15;
    int tok = rest >> 4;
    int s = tok & (SEQ - 1);
    float4 f = ((const float4*)F)[s * 64 + i];
    size_t off = (size_t)tok * D_MODEL + hh * HDIM + i * 2;
    float x0 = b2f(Qb[off]), x1 = b2f(Qb[off + 1]);
    Qb[off] = f2b(x0 * f.x + x1 * f.y);
    Qb[off + 1] = f2b(x0 * f.z + x1 * f.w);
    x0 = b2f(Kb[off]); x1 = b2f(Kb[off + 1]);
    Kb[off] = f2b(x0 * f.x + x1 * f.y);
    Kb[off + 1] = f2b(x0 * f.z + x1 * f.w);
  }
}

// ---------------- flash v4 (R11 winner): swapped softmax + T14 reg-staged K/V ----
__global__ __launch_bounds__(256) void k_flash4(const u16* __restrict__ Q,
                                                const u16* __restrict__ Kb,
                                                const u16* __restrict__ VT,
                                                u16* __restrict__ O) {
  __shared__ u16 Kt[64 * 128];        // [key][d], slot^=(key&7)
  __shared__ u16 Vt[128 * 64];        // [d][k],  slot^=(d&7)
  __shared__ u16 Pl[4][2][16 * 72];   // per-wave, per-qg: [q 16][k 64], stride 72
  const int tid = threadIdx.x;
  const int w = tid >> 6, lane = tid & 63;
  const int lo = lane & 15, hi = lane >> 4;
  const int qt = blockIdx.x, bh = blockIdx.y;
  const int b = bh >> 4, h = bh & 15;
  const size_t qrow0 = (size_t)b * SEQ + qt * 128 + w * 32;
  const float SC = 0.08838834764831845f * 1.4426950408889634f;  // scale * log2(e)

  bf16x8 aQ[2][4];
#pragma unroll
  for (int qg = 0; qg < 2; qg++)
#pragma unroll
    for (int kb = 0; kb < 4; kb++)
      aQ[qg][kb] = *(const bf16x8*)(Q + (qrow0 + qg * 16 + lo) * D_MODEL + h * HDIM + kb * 32 + hi * 8);

  float m_s[2] = {-3.0e38f, -3.0e38f}, l_s[2] = {0.f, 0.f};
  f32x4 oacc[2][8];
#pragma unroll
  for (int qg = 0; qg < 2; qg++)
#pragma unroll
    for (int d = 0; d < 8; d++) oacc[qg][d] = (f32x4){0.f, 0.f, 0.f, 0.f};

  const int krowL = tid >> 4;
  const int kslot = (tid & 15) ^ (krowL & 7);
  const int vrowL = tid >> 3;
  const int vslot = (tid & 7) ^ (vrowL & 7);
  const u16* Kbase = Kb + (size_t)b * SEQ * D_MODEL + h * HDIM;
  const u16* Vbase = VT + (size_t)bh * HDIM * SEQ;
  unsigned* Plw = (unsigned*)&Pl[w][0][0];  // u32 view, qg stride 576

  bf16x8 kreg[4], vreg[4];
  auto issue = [&](int kt) {
#pragma unroll
    for (int t = 0; t < 4; t++) {
      int row = t * 16 + krowL;
      kreg[t] = *(const bf16x8*)(Kbase + (size_t)(kt * 64 + row) * D_MODEL + kslot * 8);
    }
#pragma unroll
    for (int t = 0; t < 4; t++) {
      int row = t * 32 + vrowL;
      vreg[t] = *(const bf16x8*)(Vbase + (size_t)row * SEQ + kt * 64 + vslot * 8);
    }
  };
  auto commit = [&]() {
#pragma unroll
    for (int t = 0; t < 4; t++)
      *(bf16x8*)((char*)Kt + t * 4096 + tid * 16) = kreg[t];
#pragma unroll
    for (int t = 0; t < 4; t++)
      *(bf16x8*)((char*)Vt + t * 4096 + tid * 16) = vreg[t];
  };

  // prologue: tile 0 into LDS
  issue(0);
  commit();
  BARRIER();

  const int NT = SEQ / 64;
  for (int kt = 0; kt < NT; kt++) {
    if (kt + 1 < NT) {
      issue(kt + 1);  // long-latency loads hide under this iteration's compute
      SB0();
    }

    // ---- QK^T (swapped): S^T[key][q] ----
    f32x4 sf[2][4];
#pragma unroll
    for (int cb = 0; cb < 4; cb++) {
      bf16x8 kA[4];
#pragma unroll
      for (int kb = 0; kb < 4; kb++) {
        int ps = (kb * 4 + hi) ^ (lo & 7);
        kA[kb] = *(const bf16x8*)(Kt + (cb * 16 + lo) * 128 + ps * 8);
      }
#pragma unroll
      for (int qg = 0; qg < 2; qg++) {
        f32x4 s = (f32x4){0.f, 0.f, 0.f, 0.f};
#pragma unroll
        for (int kb = 0; kb < 4; kb++)
          s = __builtin_amdgcn_mfma_f32_16x16x32_bf16(kA[kb], aQ[qg][kb], s, 0, 0, 0);
        sf[qg][cb] = s;
      }
    }

    // ---- softmax: lane-local over 16 keys + 2 wide shfls ----
    float tsc[2];
    bool ok = true;
#pragma unroll
    for (int qg = 0; qg < 2; qg++) {
      float t0 = fmaxf(fmaxf(sf[qg][0][0], sf[qg][0][1]), fmaxf(sf[qg][0][2], sf[qg][0][3]));
      float t1 = fmaxf(fmaxf(sf[qg][1][0], sf[qg][1][1]), fmaxf(sf[qg][1][2], sf[qg][1][3]));
      float t2 = fmaxf(fmaxf(sf[qg][2][0], sf[qg][2][1]), fmaxf(sf[qg][2][2], sf[qg][2][3]));
      float t3 = fmaxf(fmaxf(sf[qg][3][0], sf[qg][3][1]), fmaxf(sf[qg][3][2], sf[qg][3][3]));
      float t = fmaxf(fmaxf(t0, t1), fmaxf(t2, t3));
      t = fmaxf(t, __shfl_xor(t, 16));
      t = fmaxf(t, __shfl_xor(t, 32));
      tsc[qg] = t * SC;
      ok = ok && (tsc[qg] - m_s[qg] <= 11.5f);
    }
    bool skip = __all(ok);
#pragma unroll
    for (int qg = 0; qg < 2; qg++) {
      float mm = m_s[qg];
      if (!skip) {
        mm = fmaxf(m_s[qg], tsc[qg]);
        float alpha = exp2f(m_s[qg] - mm);
        l_s[qg] *= alpha;
#pragma unroll
        for (int d = 0; d < 8; d++) oacc[qg][d] *= alpha;
        m_s[qg] = mm;
      }
      float rs = 0.f;
#pragma unroll
      for (int cb = 0; cb < 4; cb++) {
        float p0 = exp2f(sf[qg][cb][0] * SC - mm);
        float p1 = exp2f(sf[qg][cb][1] * SC - mm);
        float p2 = exp2f(sf[qg][cb][2] * SC - mm);
        float p3 = exp2f(sf[qg][cb][3] * SC - mm);
        rs += (p0 + p1) + (p2 + p3);
        unsigned pk0, pk1;
        asm("v_cvt_pk_bf16_f32 %0, %1, %2" : "=v"(pk0) : "v"(p0), "v"(p1));
        asm("v_cvt_pk_bf16_f32 %0, %1, %2" : "=v"(pk1) : "v"(p2), "v"(p3));
        Plw[qg * 576 + lo * 36 + cb * 8 + hi * 2 + 0] = pk0;
        Plw[qg * 576 + lo * 36 + cb * 8 + hi * 2 + 1] = pk1;
      }
      rs += __shfl_xor(rs, 16);
      rs += __shfl_xor(rs, 32);
      l_s[qg] += rs;
    }
    LGKM0();

    // ---- PV (swapped): O^T[d][q] ----
    bf16x8 aP[2][2];
#pragma unroll
    for (int qg = 0; qg < 2; qg++)
#pragma unroll
      for (int ks = 0; ks < 2; ks++)
        aP[qg][ks] = *(const bf16x8*)(&Pl[w][qg][lo * 72 + ks * 32 + hi * 8]);
#pragma unroll
    for (int db = 0; db < 8; db++) {
      bf16x8 vA[2];
#pragma unroll
      for (int ks = 0; ks < 2; ks++) {
        int ps = (ks * 4 + hi) ^ (lo & 7);
        vA[ks] = *(const bf16x8*)(Vt + (db * 16 + lo) * 64 + ps * 8);
      }
#pragma unroll
      for (int qg = 0; qg < 2; qg++)
#pragma unroll
        for (int ks = 0; ks < 2; ks++)
          oacc[qg][db] = __builtin_amdgcn_mfma_f32_16x16x32_bf16(vA[ks], aP[qg][ks], oacc[qg][db], 0, 0, 0);
    }

    if (kt + 1 < NT) {
      BARRIER();   // all waves done reading tile kt
      commit();    // implicit vmcnt waits only on our own loads (already landed)
      BARRIER();   // tile kt+1 visible
    }
  }

  // ---- epilogue: O^T[d][q] -> O[q][d], 8B packed stores ----
#pragma unroll
  for (int qg = 0; qg < 2; qg++) {
    float inv = 1.f / l_s[qg];
    size_t rowoff = (qrow0 + qg * 16 + lo) * D_MODEL + h * HDIM;
#pragma unroll
    for (int db = 0; db < 8; db++) {
      s16x4 o;
#pragma unroll
      for (int r = 0; r < 4; r++) o[r] = (short)f2b(oacc[qg][db][r] * inv);
      *(s16x4*)(O + rowoff + db * 16 + hi * 4) = o;
    }
  }
}

extern "C" void kernel_launch(void* const* d_in, const int* in_sizes, int n_in,
                              void* d_out, int out_size, void* d_ws, size_t ws_size,
                              hipStream_t stream) {
  (void)in_sizes; (void)n_in; (void)out_size; (void)ws_size;
  const float* x  = (const float*)d_in[0];
  const float* fc = (const float*)d_in[1];
  const float* wq = (const float*)d_in[2];
  const float* wk = (const float*)d_in[3];
  const float* wv = (const float*)d_in[4];
  const float* wo = (const float*)d_in[5];
  const float* bo = (const float*)d_in[6];
  const float* w1 = (const float*)d_in[7];
  const float* w3 = (const float*)d_in[8];
  const float* w2 = (const float*)d_in[9];
  const float* ga = (const float*)d_in[10];
  const float* gf = (const float*)d_in[11];
  float* out = (float*)d_out;  // also holds hres (fp32) between sublayers

  // ---- workspace (~185 MB) ----
  char* p = (char*)d_ws;
  auto alloc = [&](size_t bytes) { char* r = p; p += (bytes + 255) & ~(size_t)255; return r; };
  u16* xn   = (u16*)alloc((size_t)MTOK * D_MODEL * 2);  // A
  u16* qb   = (u16*)alloc((size_t)MTOK * D_MODEL * 2);  // B: reused as hn
  u16* kb   = (u16*)alloc((size_t)MTOK * D_MODEL * 2);  // C
  u16* vb   = (u16*)alloc((size_t)MTOK * D_MODEL * 2);  // D: used as ob (flash out)
  u16* x1   = (u16*)alloc((size_t)MTOK * HP2 * 2);      // E: vbt before W13, then x1
  u16* w13i = (u16*)alloc((size_t)11264 * D_MODEL * 2); // F: interleaved W1/W3 weights
  u16* wsl  = (u16*)alloc((size_t)3 * D_MODEL * D_MODEL * 2);  // G: shared weight slot
  u16* vbt = x1;  // [32 bh][128 d][2048 s] — dead until W13 overwrites
  u16* ob  = vb;
  u16* hn  = qb;

  // ---- attention sublayer ----
  k_rmsnorm<<<MTOK, 256, 0, stream>>>(x, ga, xn);
  k_conv3<<<1536, 256, 0, stream>>>(wq, wk, wv, wsl);
  // QKV fused; V written directly transposed into vbt
  k_gemm2<4, 1><<<dim3(6144 / 256, MTOK / 256), 512, 0, stream>>>(
      xn, wsl, nullptr, qb, kb, vbt, nullptr, nullptr, nullptr, MTOK, 6144, D_MODEL);
  k_rope<<<1024, 256, 0, stream>>>(qb, kb, fc);
  dim3 gfl(SEQ / 128, BATCH * NHEADS);
  k_flash4<<<gfl, 256, 0, stream>>>(qb, kb, vbt, ob);
  k_conv8<<<1024, 256, 0, stream>>>(wo, wsl, D_MODEL * D_MODEL / 8);
  k_gemm2<2, 2><<<dim3(2048 / 128, MTOK / 256), 512, 0, stream>>>(
      ob, wsl, nullptr, out, nullptr, nullptr, bo, x, nullptr, MTOK, D_MODEL, D_MODEL);

  // ---- FFN sublayer (hres lives in `out`) ----
  k_rmsnorm<<<MTOK, 256, 0, stream>>>(out, gf, hn);  // hn overwrites qb (dead)
  k_convw13<<<2048, 256, 0, stream>>>(w1, w3, w13i);
  // W13 fused: N = 11264 fragment-interleaved; epilogue = reg-only silu(x1)*x3 -> x1
  k_gemm2<4, 6><<<dim3(11264 / 256, MTOK / 256), 512, 0, stream>>>(
      hn, w13i, nullptr, x1, nullptr, nullptr, nullptr, nullptr, nullptr, MTOK, 11264, D_MODEL);
  k_convw2<<<1024, 256, 0, stream>>>(w2, wsl);
  k_gemm2<2, 3><<<dim3(2048 / 128, MTOK / 256), 512, 0, stream>>>(
      x1, wsl, nullptr, out, nullptr, nullptr, nullptr, out, nullptr, MTOK, D_MODEL, HP2);
}

// Round 14
// 683.575 us; speedup vs baseline: 1.0235x; 1.0063x over previous
//
#include <hip/hip_runtime.h>

#define D_MODEL 2048
#define NHEADS 16
#define HDIM 128
#define HIDDEN_ 5461
#define HP2 5632
#define BATCH 2
#define SEQ 2048
#define MTOK 4096

typedef unsigned short u16;
typedef __attribute__((ext_vector_type(8))) short bf16x8;
typedef __attribute__((ext_vector_type(4))) float f32x4;
typedef __attribute__((ext_vector_type(4))) short s16x4;

__device__ __forceinline__ u16 f2b(float f) {
  union { float f; unsigned u; } v; v.f = f;
  return (u16)((v.u + 0x7FFFu + ((v.u >> 16) & 1u)) >> 16);
}
__device__ __forceinline__ float b2f(u16 u) {
  union { unsigned u; float f; } v; v.u = ((unsigned)u) << 16;
  return v.f;
}
__device__ __forceinline__ void gload16(const void* g, void* l) {
  __builtin_amdgcn_global_load_lds(
      (const __attribute__((address_space(1))) unsigned int*)g,
      (__attribute__((address_space(3))) unsigned int*)l, 16, 0, 0);
}

#define SB0() __builtin_amdgcn_sched_barrier(0)
#define BARRIER() do { SB0(); __builtin_amdgcn_s_barrier(); SB0(); } while (0)
#define LGKM0() do { asm volatile("s_waitcnt lgkmcnt(0)" ::: "memory"); SB0(); } while (0)

// ---------------- conversions ----------------
__global__ __launch_bounds__(256) void k_conv8(const float* __restrict__ src,
                                               u16* __restrict__ dst, int n8) {
  int stride = gridDim.x * 256;
  for (int i = blockIdx.x * 256 + threadIdx.x; i < n8; i += stride) {
    const float4* s = (const float4*)src + (size_t)i * 2;
    float4 a = s[0], b = s[1];
    bf16x8 o;
    o[0] = f2b(a.x); o[1] = f2b(a.y); o[2] = f2b(a.z); o[3] = f2b(a.w);
    o[4] = f2b(b.x); o[5] = f2b(b.y); o[6] = f2b(b.z); o[7] = f2b(b.w);
    ((bf16x8*)dst)[i] = o;
  }
}

__global__ __launch_bounds__(256) void k_conv3(const float* __restrict__ s0,
                                               const float* __restrict__ s1,
                                               const float* __restrict__ s2,
                                               u16* __restrict__ dst) {
  const int n8 = D_MODEL * D_MODEL / 8;  // 2^19
  int total = 3 * n8;
  int stride = gridDim.x * 256;
  for (int i = blockIdx.x * 256 + threadIdx.x; i < total; i += stride) {
    int seg = i >> 19, j = i & (n8 - 1);
    const float* s = (seg == 0) ? s0 : (seg == 1 ? s1 : s2);
    const float4* sp = (const float4*)s + (size_t)j * 2;
    float4 a = sp[0], b = sp[1];
    bf16x8 o;
    o[0] = f2b(a.x); o[1] = f2b(a.y); o[2] = f2b(a.z); o[3] = f2b(a.w);
    o[4] = f2b(b.x); o[5] = f2b(b.y); o[6] = f2b(b.z); o[7] = f2b(b.w);
    ((bf16x8*)dst)[i] = o;
  }
}

// FFN weight conversion, one launch:
//  part 1: W13 fragment-interleaved (frag nf even -> w1, odd -> w3, same cols)
//  part 2: w2 [2048][5461] fp32 -> [2048][5632] bf16 (K-pad)
__global__ __launch_bounds__(256) void k_convffn(const float* __restrict__ w1,
                                                 const float* __restrict__ w3,
                                                 const float* __restrict__ w2,
                                                 u16* __restrict__ d13,
                                                 u16* __restrict__ d2) {
  const int n13 = (11264 * D_MODEL) / 8;
  const int n2 = 2048 * (HP2 / 8);
  int total = n13 + n2;
  int stride = gridDim.x * 256;
  for (int i = blockIdx.x * 256 + threadIdx.x; i < total; i += stride) {
    if (i < n13) {
      int r = i >> 8, c8 = i & 255;
      int g = r >> 8, rem = r & 255;
      int wcb = rem >> 6, t = rem & 63, pp = t >> 4, ll = t & 15;
      int srow = g * 128 + wcb * 32 + (pp >> 1) * 16 + ll;
      bf16x8 o;
      if (srow < HIDDEN_) {
        const float* s = (pp & 1) ? w3 : w1;
        const float4* sp = (const float4*)(s + (size_t)srow * D_MODEL + c8 * 8);
        float4 a = sp[0], b = sp[1];
        o[0] = f2b(a.x); o[1] = f2b(a.y); o[2] = f2b(a.z); o[3] = f2b(a.w);
        o[4] = f2b(b.x); o[5] = f2b(b.y); o[6] = f2b(b.z); o[7] = f2b(b.w);
      } else {
        o = (bf16x8){0, 0, 0, 0, 0, 0, 0, 0};
      }
      ((bf16x8*)d13)[i] = o;
    } else {
      int k = i - n13;
      int r = k / 704, c8 = k % 704;
      int c = c8 * 8;
      const float* s = w2 + (size_t)r * HIDDEN_ + c;
      bf16x8 o;
#pragma unroll
      for (int e = 0; e < 8; e++) o[e] = (c + e < HIDDEN_) ? f2b(s[e]) : (u16)0;
      ((bf16x8*)d2)[k] = o;
    }
  }
}

// ---------------- rmsnorm (fp32 in, bf16 out) ----------------
__global__ __launch_bounds__(256) void k_rmsnorm(const float* __restrict__ X,
                                                 const float* __restrict__ G,
                                                 u16* __restrict__ Out) {
  int row = blockIdx.x;
  int tid = threadIdx.x;
  const float4* x4 = (const float4*)(X + (size_t)row * D_MODEL);
  float4 a = x4[tid * 2], b = x4[tid * 2 + 1];
  float ss = a.x * a.x + a.y * a.y + a.z * a.z + a.w * a.w +
             b.x * b.x + b.y * b.y + b.z * b.z + b.w * b.w;
#pragma unroll
  for (int off = 1; off < 64; off <<= 1) ss += __shfl_xor(ss, off);
  __shared__ float part[4];
  if ((tid & 63) == 0) part[tid >> 6] = ss;
  __syncthreads();
  float rstd = rsqrtf((part[0] + part[1] + part[2] + part[3]) * (1.0f / D_MODEL) + 1e-6f);
  const float4* g4 = (const float4*)G;
  float4 ga = g4[tid * 2], gb = g4[tid * 2 + 1];
  bf16x8 o;
  o[0] = f2b(a.x * rstd * ga.x); o[1] = f2b(a.y * rstd * ga.y);
  o[2] = f2b(a.z * rstd * ga.z); o[3] = f2b(a.w * rstd * ga.w);
  o[4] = f2b(b.x * rstd * gb.x); o[5] = f2b(b.y * rstd * gb.y);
  o[6] = f2b(b.z * rstd * gb.z); o[7] = f2b(b.w * rstd * gb.w);
  *((bf16x8*)(Out + (size_t)row * D_MODEL) + tid) = o;
}

// ================= 256x(BN) 8-phase GEMM, LDS bank-swizzled =================
// COLM: XCD-chunk tile order. 0 = row-major (tn fastest; A-panel reuse per XCD),
// 1 = col-major (tm fastest; B-panel reuse per XCD). Pick per GEMM to minimize
// per-XCD panel fetch: QKV/W13 -> 1, WO/W2 -> 0.
// EPI: 0 bf16 | 1 qkv split (V transposed to O2=[bh][d][s]) | 2 f32+bias+res |
//      3 f32+res | 6 W13 reg-fused silu
template <int WN, int EPI, int COLM>
__global__ __launch_bounds__(512, 2) void k_gemm2(const u16* __restrict__ A,
                                                  const u16* __restrict__ Bw,
                                                  void* __restrict__ O0,
                                                  void* __restrict__ O1,
                                                  void* __restrict__ O2,
                                                  const float* __restrict__ bias,
                                                  const float* __restrict__ res,
                                                  int M, int N, int K) {
  constexpr int BN = WN * 64;
  constexpr int PB = BN * 64;  // B plane bytes
  __shared__ __align__(128) char lds[65536 + 4 * PB];
  const int tid = threadIdx.x;
  const int w = tid >> 6, lane = tid & 63;
  const int lo = lane & 15, hi = lane >> 4;
  const int wr = w >> 2, wc = w & 3;

  const int ntN = N / BN;
  const int ntM = M >> 8;
  const int nwg = gridDim.x * gridDim.y;
  const int flat = blockIdx.y * gridDim.x + blockIdx.x;
  const int swz = (flat & 7) * (nwg >> 3) + (flat >> 3);
  int tm, tn;
  if (COLM) { tm = swz % ntM; tn = swz / ntM; }
  else      { tm = swz / ntN; tn = swz % ntN; }
  const int m0 = tm * 256, n0 = tn * BN;

  const u16* bbase = Bw + (size_t)n0 * K;

  const int sslot = ((tid & 3) ^ ((tid >> 3) & 3)) * 8;  // pre-swizzled source slot

  auto stA = [&](int nb, int kk, int k0) {
#pragma unroll
    for (int j = 0; j < 2; ++j) {
      int row = j * 128 + (tid >> 2);
      const u16* g = A + (size_t)(m0 + row) * K + k0 + kk * 32 + sslot;
      gload16(g, lds + nb * 32768 + kk * 16384 + j * 8192 + tid * 16);
    }
  };
  auto stB = [&](int nb, int kk, int k0) {
#pragma unroll
    for (int j = 0; j < WN / 2; ++j) {
      int row = j * 128 + (tid >> 2);
      const u16* g = bbase + (size_t)row * K + k0 + kk * 32 + sslot;
      gload16(g, lds + 65536 + nb * 2 * PB + kk * PB + j * 8192 + tid * 16);
    }
  };
  auto ldA = [&](int buf, int kk, int mf) {
    int row = wr * 128 + mf * 16 + lo;
    int sl = hi ^ ((row >> 1) & 3);
    return *(const bf16x8*)(lds + buf * 32768 + kk * 16384 + row * 64 + sl * 16);
  };
  auto ldB = [&](int buf, int kk, int nf) {
    int row = wc * (WN * 16) + nf * 16 + lo;
    int sl = hi ^ ((row >> 1) & 3);
    return *(const bf16x8*)(lds + 65536 + buf * 2 * PB + kk * PB + row * 64 + sl * 16);
  };
#define VMCNT_CONFIRM()                                             \
  do {                                                              \
    if constexpr (WN == 4)                                          \
      asm volatile("s_waitcnt vmcnt(4)" ::: "memory");              \
    else                                                            \
      asm volatile("s_waitcnt vmcnt(3)" ::: "memory");              \
    SB0();                                                          \
  } while (0)

  f32x4 acc[8][WN];
#pragma unroll
  for (int i = 0; i < 8; i++)
#pragma unroll
    for (int j = 0; j < WN; j++) acc[i][j] = (f32x4){0.f, 0.f, 0.f, 0.f};

  stA(0, 0, 0);
  stB(0, 0, 0);
  stA(0, 1, 0);
  stB(0, 1, 0);
  VMCNT_CONFIRM();
  BARRIER();

  const int KT = K / 64;
  for (int kt = 0; kt < KT; ++kt) {
    const int buf = kt & 1, nb = buf ^ 1;
    int kn = (kt + 1) * 64;
    if (kn >= K) kn = 0;  // dummy stage on last tile (never consumed)
    bf16x8 aF[4], bF[WN];

    // ---- phase 1: kk=0, m-frags 0..3 ----
#pragma unroll
    for (int i = 0; i < 4; i++) aF[i] = ldA(buf, 0, i);
#pragma unroll
    for (int j = 0; j < WN; j++) bF[j] = ldB(buf, 0, j);
    stA(nb, 0, kn);
    BARRIER();
    LGKM0();
    __builtin_amdgcn_s_setprio(1);
#pragma unroll
    for (int i = 0; i < 4; i++)
#pragma unroll
      for (int j = 0; j < WN; j++)
        acc[i][j] = __builtin_amdgcn_mfma_f32_16x16x32_bf16(aF[i], bF[j], acc[i][j], 0, 0, 0);
    __builtin_amdgcn_s_setprio(0);
    BARRIER();

    // ---- phase 2: kk=0, m-frags 4..7 ----
#pragma unroll
    for (int i = 0; i < 4; i++) aF[i] = ldA(buf, 0, 4 + i);
    stB(nb, 0, kn);
    VMCNT_CONFIRM();
    BARRIER();
    LGKM0();
    __builtin_amdgcn_s_setprio(1);
#pragma unroll
    for (int i = 0; i < 4; i++)
#pragma unroll
      for (int j = 0; j < WN; j++)
        acc[4 + i][j] = __builtin_amdgcn_mfma_f32_16x16x32_bf16(aF[i], bF[j], acc[4 + i][j], 0, 0, 0);
    __builtin_amdgcn_s_setprio(0);
    BARRIER();

    // ---- phase 3: kk=1, m-frags 0..3 ----
#pragma unroll
    for (int i = 0; i < 4; i++) aF[i] = ldA(buf, 1, i);
#pragma unroll
    for (int j = 0; j < WN; j++) bF[j] = ldB(buf, 1, j);
    stA(nb, 1, kn);
    BARRIER();
    LGKM0();
    __builtin_amdgcn_s_setprio(1);
#pragma unroll
    for (int i = 0; i < 4; i++)
#pragma unroll
      for (int j = 0; j < WN; j++)
        acc[i][j] = __builtin_amdgcn_mfma_f32_16x16x32_bf16(aF[i], bF[j], acc[i][j], 0, 0, 0);
    __builtin_amdgcn_s_setprio(0);
    BARRIER();

    // ---- phase 4: kk=1, m-frags 4..7 ----
#pragma unroll
    for (int i = 0; i < 4; i++) aF[i] = ldA(buf, 1, 4 + i);
    stB(nb, 1, kn);
    VMCNT_CONFIRM();
    BARRIER();
    LGKM0();
    __builtin_amdgcn_s_setprio(1);
#pragma unroll
    for (int i = 0; i < 4; i++)
#pragma unroll
      for (int j = 0; j < WN; j++)
        acc[4 + i][j] = __builtin_amdgcn_mfma_f32_16x16x32_bf16(aF[i], bF[j], acc[4 + i][j], 0, 0, 0);
    __builtin_amdgcn_s_setprio(0);
    BARRIER();
  }

  // ---- epilogue ----
  if (EPI == 6) {
    int c0 = n0 >> 1;
#pragma unroll
    for (int i = 0; i < 8; i++) {
#pragma unroll
      for (int jp = 0; jp < WN; jp += 2) {
        int colL = wc * 32 + (jp >> 1) * 16 + lo;
#pragma unroll
        for (int r = 0; r < 4; r++) {
          int row = m0 + wr * 128 + i * 16 + hi * 4 + r;
          float v1 = acc[i][jp][r];
          float v3 = acc[i][jp + 1][r];
          float sig = 1.f / (1.f + __expf(-v1));
          ((u16*)O0)[(size_t)row * 5632 + c0 + colL] = f2b(v1 * sig * v3);
        }
      }
    }
    return;
  }
  if (EPI == 1) {
    int seg = n0 >> 11;
    int c0 = n0 & 2047;
    if (seg < 2) {
      u16* qkvout = (u16*)(seg == 0 ? O0 : O1);
#pragma unroll
      for (int i = 0; i < 8; i++)
#pragma unroll
        for (int j = 0; j < WN; j++) {
          int colL = wc * (WN * 16) + j * 16 + lo;
#pragma unroll
          for (int r = 0; r < 4; r++) {
            int row = m0 + wr * 128 + i * 16 + hi * 4 + r;
            qkvout[(size_t)row * 2048 + c0 + colL] = f2b(acc[i][j][r]);
          }
        }
    } else {
      // V written transposed: vt[((b*16+h)*128 + d) * 2048 + s], s-packed 8B stores
      u16* vt = (u16*)O2;
      int b = m0 >> 11;
      int sb = m0 & 2047;
#pragma unroll
      for (int i = 0; i < 8; i++)
#pragma unroll
        for (int j = 0; j < WN; j++) {
          int col = c0 + wc * (WN * 16) + j * 16 + lo;
          size_t base = ((size_t)(b * 16 + (col >> 7)) * 128 + (col & 127)) * 2048;
          int s0 = sb + wr * 128 + i * 16 + hi * 4;
          s16x4 o;
#pragma unroll
          for (int r = 0; r < 4; r++) o[r] = (short)f2b(acc[i][j][r]);
          *(s16x4*)(vt + base + s0) = o;
        }
    }
    return;
  }
#pragma unroll
  for (int i = 0; i < 8; i++) {
#pragma unroll
    for (int j = 0; j < WN; j++) {
      int colL = wc * (WN * 16) + j * 16 + lo;
#pragma unroll
      for (int r = 0; r < 4; r++) {
        int row = m0 + wr * 128 + i * 16 + hi * 4 + r;
        float v = acc[i][j][r];
        if (EPI == 0) {
          ((u16*)O0)[(size_t)row * N + n0 + colL] = f2b(v);
        } else if (EPI == 2) {
          size_t idx = (size_t)row * N + n0 + colL;
          ((float*)O0)[idx] = v + bias[n0 + colL] + res[idx];
        } else if (EPI == 3) {
          size_t idx = (size_t)row * N + n0 + colL;
          ((float*)O0)[idx] = v + res[idx];
        }
      }
    }
  }
#undef VMCNT_CONFIRM
}

// ---------------- RoPE (in-place on bf16 q,k) ----------------
__global__ __launch_bounds__(256) void k_rope(u16* __restrict__ Qb, u16* __restrict__ Kb,
                                              const float* __restrict__ F) {
  int n = MTOK * (D_MODEL / 2);
  int stride = gridDim.x * 256;
  for (int t = blockIdx.x * 256 + threadIdx.x; t < n; t += stride) {
    int i = t & 63;
    int rest = t >> 6;
    int hh = rest & 15;
    int tok = rest >> 4;
    int s = tok & (SEQ - 1);
    float4 f = ((const float4*)F)[s * 64 + i];
    size_t off = (size_t)tok * D_MODEL + hh * HDIM + i * 2;
    float x0 = b2f(Qb[off]), x1 = b2f(Qb[off + 1]);
    Qb[off] = f2b(x0 * f.x + x1 * f.y);
    Qb[off + 1] = f2b(x0 * f.z + x1 * f.w);
    x0 = b2f(Kb[off]); x1 = b2f(Kb[off + 1]);
    Kb[off] = f2b(x0 * f.x + x1 * f.y);
    Kb[off + 1] = f2b(x0 * f.z + x1 * f.w);
  }
}

// ---------------- flash v4 (R11 winner): swapped softmax + T14 reg-staged K/V ----
__global__ __launch_bounds__(256) void k_flash4(const u16* __restrict__ Q,
                                                const u16* __restrict__ Kb,
                                                const u16* __restrict__ VT,
                                                u16* __restrict__ O) {
  __shared__ u16 Kt[64 * 128];        // [key][d], slot^=(key&7)
  __shared__ u16 Vt[128 * 64];        // [d][k],  slot^=(d&7)
  __shared__ u16 Pl[4][2][16 * 72];   // per-wave, per-qg: [q 16][k 64], stride 72
  const int tid = threadIdx.x;
  const int w = tid >> 6, lane = tid & 63;
  const int lo = lane & 15, hi = lane >> 4;
  const int qt = blockIdx.x, bh = blockIdx.y;
  const int b = bh >> 4, h = bh & 15;
  const size_t qrow0 = (size_t)b * SEQ + qt * 128 + w * 32;
  const float SC = 0.08838834764831845f * 1.4426950408889634f;  // scale * log2(e)

  bf16x8 aQ[2][4];
#pragma unroll
  for (int qg = 0; qg < 2; qg++)
#pragma unroll
    for (int kb = 0; kb < 4; kb++)
      aQ[qg][kb] = *(const bf16x8*)(Q + (qrow0 + qg * 16 + lo) * D_MODEL + h * HDIM + kb * 32 + hi * 8);

  float m_s[2] = {-3.0e38f, -3.0e38f}, l_s[2] = {0.f, 0.f};
  f32x4 oacc[2][8];
#pragma unroll
  for (int qg = 0; qg < 2; qg++)
#pragma unroll
    for (int d = 0; d < 8; d++) oacc[qg][d] = (f32x4){0.f, 0.f, 0.f, 0.f};

  const int krowL = tid >> 4;
  const int kslot = (tid & 15) ^ (krowL & 7);
  const int vrowL = tid >> 3;
  const int vslot = (tid & 7) ^ (vrowL & 7);
  const u16* Kbase = Kb + (size_t)b * SEQ * D_MODEL + h * HDIM;
  const u16* Vbase = VT + (size_t)bh * HDIM * SEQ;
  unsigned* Plw = (unsigned*)&Pl[w][0][0];  // u32 view, qg stride 576

  bf16x8 kreg[4], vreg[4];
  auto issue = [&](int kt) {
#pragma unroll
    for (int t = 0; t < 4; t++) {
      int row = t * 16 + krowL;
      kreg[t] = *(const bf16x8*)(Kbase + (size_t)(kt * 64 + row) * D_MODEL + kslot * 8);
    }
#pragma unroll
    for (int t = 0; t < 4; t++) {
      int row = t * 32 + vrowL;
      vreg[t] = *(const bf16x8*)(Vbase + (size_t)row * SEQ + kt * 64 + vslot * 8);
    }
  };
  auto commit = [&]() {
#pragma unroll
    for (int t = 0; t < 4; t++)
      *(bf16x8*)((char*)Kt + t * 4096 + tid * 16) = kreg[t];
#pragma unroll
    for (int t = 0; t < 4; t++)
      *(bf16x8*)((char*)Vt + t * 4096 + tid * 16) = vreg[t];
  };

  // prologue: tile 0 into LDS
  issue(0);
  commit();
  BARRIER();

  const int NT = SEQ / 64;
  for (int kt = 0; kt < NT; kt++) {
    if (kt + 1 < NT) {
      issue(kt + 1);  // long-latency loads hide under this iteration's compute
      SB0();
    }

    // ---- QK^T (swapped): S^T[key][q] ----
    f32x4 sf[2][4];
#pragma unroll
    for (int cb = 0; cb < 4; cb++) {
      bf16x8 kA[4];
#pragma unroll
      for (int kb = 0; kb < 4; kb++) {
        int ps = (kb * 4 + hi) ^ (lo & 7);
        kA[kb] = *(const bf16x8*)(Kt + (cb * 16 + lo) * 128 + ps * 8);
      }
#pragma unroll
      for (int qg = 0; qg < 2; qg++) {
        f32x4 s = (f32x4){0.f, 0.f, 0.f, 0.f};
#pragma unroll
        for (int kb = 0; kb < 4; kb++)
          s = __builtin_amdgcn_mfma_f32_16x16x32_bf16(kA[kb], aQ[qg][kb], s, 0, 0, 0);
        sf[qg][cb] = s;
      }
    }

    // ---- softmax: lane-local over 16 keys + 2 wide shfls ----
    float tsc[2];
    bool ok = true;
#pragma unroll
    for (int qg = 0; qg < 2; qg++) {
      float t0 = fmaxf(fmaxf(sf[qg][0][0], sf[qg][0][1]), fmaxf(sf[qg][0][2], sf[qg][0][3]));
      float t1 = fmaxf(fmaxf(sf[qg][1][0], sf[qg][1][1]), fmaxf(sf[qg][1][2], sf[qg][1][3]));
      float t2 = fmaxf(fmaxf(sf[qg][2][0], sf[qg][2][1]), fmaxf(sf[qg][2][2], sf[qg][2][3]));
      float t3 = fmaxf(fmaxf(sf[qg][3][0], sf[qg][3][1]), fmaxf(sf[qg][3][2], sf[qg][3][3]));
      float t = fmaxf(fmaxf(t0, t1), fmaxf(t2, t3));
      t = fmaxf(t, __shfl_xor(t, 16));
      t = fmaxf(t, __shfl_xor(t, 32));
      tsc[qg] = t * SC;
      ok = ok && (tsc[qg] - m_s[qg] <= 11.5f);
    }
    bool skip = __all(ok);
#pragma unroll
    for (int qg = 0; qg < 2; qg++) {
      float mm = m_s[qg];
      if (!skip) {
        mm = fmaxf(m_s[qg], tsc[qg]);
        float alpha = exp2f(m_s[qg] - mm);
        l_s[qg] *= alpha;
#pragma unroll
        for (int d = 0; d < 8; d++) oacc[qg][d] *= alpha;
        m_s[qg] = mm;
      }
      float rs = 0.f;
#pragma unroll
      for (int cb = 0; cb < 4; cb++) {
        float p0 = exp2f(sf[qg][cb][0] * SC - mm);
        float p1 = exp2f(sf[qg][cb][1] * SC - mm);
        float p2 = exp2f(sf[qg][cb][2] * SC - mm);
        float p3 = exp2f(sf[qg][cb][3] * SC - mm);
        rs += (p0 + p1) + (p2 + p3);
        unsigned pk0, pk1;
        asm("v_cvt_pk_bf16_f32 %0, %1, %2" : "=v"(pk0) : "v"(p0), "v"(p1));
        asm("v_cvt_pk_bf16_f32 %0, %1, %2" : "=v"(pk1) : "v"(p2), "v"(p3));
        Plw[qg * 576 + lo * 36 + cb * 8 + hi * 2 + 0] = pk0;
        Plw[qg * 576 + lo * 36 + cb * 8 + hi * 2 + 1] = pk1;
      }
      rs += __shfl_xor(rs, 16);
      rs += __shfl_xor(rs, 32);
      l_s[qg] += rs;
    }
    LGKM0();

    // ---- PV (swapped): O^T[d][q] ----
    bf16x8 aP[2][2];
#pragma unroll
    for (int qg = 0; qg < 2; qg++)
#pragma unroll
      for (int ks = 0; ks < 2; ks++)
        aP[qg][ks] = *(const bf16x8*)(&Pl[w][qg][lo * 72 + ks * 32 + hi * 8]);
#pragma unroll
    for (int db = 0; db < 8; db++) {
      bf16x8 vA[2];
#pragma unroll
      for (int ks = 0; ks < 2; ks++) {
        int ps = (ks * 4 + hi) ^ (lo & 7);
        vA[ks] = *(const bf16x8*)(Vt + (db * 16 + lo) * 64 + ps * 8);
      }
#pragma unroll
      for (int qg = 0; qg < 2; qg++)
#pragma unroll
        for (int ks = 0; ks < 2; ks++)
          oacc[qg][db] = __builtin_amdgcn_mfma_f32_16x16x32_bf16(vA[ks], aP[qg][ks], oacc[qg][db], 0, 0, 0);
    }

    if (kt + 1 < NT) {
      BARRIER();   // all waves done reading tile kt
      commit();    // implicit vmcnt waits only on our own loads (already landed)
      BARRIER();   // tile kt+1 visible
    }
  }

  // ---- epilogue: O^T[d][q] -> O[q][d], 8B packed stores ----
#pragma unroll
  for (int qg = 0; qg < 2; qg++) {
    float inv = 1.f / l_s[qg];
    size_t rowoff = (qrow0 + qg * 16 + lo) * D_MODEL + h * HDIM;
#pragma unroll
    for (int db = 0; db < 8; db++) {
      s16x4 o;
#pragma unroll
      for (int r = 0; r < 4; r++) o[r] = (short)f2b(oacc[qg][db][r] * inv);
      *(s16x4*)(O + rowoff + db * 16 + hi * 4) = o;
    }
  }
}

extern "C" void kernel_launch(void* const* d_in, const int* in_sizes, int n_in,
                              void* d_out, int out_size, void* d_ws, size_t ws_size,
                              hipStream_t stream) {
  (void)in_sizes; (void)n_in; (void)out_size; (void)ws_size;
  const float* x  = (const float*)d_in[0];
  const float* fc = (const float*)d_in[1];
  const float* wq = (const float*)d_in[2];
  const float* wk = (const float*)d_in[3];
  const float* wv = (const float*)d_in[4];
  const float* wo = (const float*)d_in[5];
  const float* bo = (const float*)d_in[6];
  const float* w1 = (const float*)d_in[7];
  const float* w3 = (const float*)d_in[8];
  const float* w2 = (const float*)d_in[9];
  const float* ga = (const float*)d_in[10];
  const float* gf = (const float*)d_in[11];
  float* out = (float*)d_out;  // also holds hres (fp32) between sublayers

  // ---- workspace (~185 MB) ----
  char* p = (char*)d_ws;
  auto alloc = [&](size_t bytes) { char* r = p; p += (bytes + 255) & ~(size_t)255; return r; };
  u16* xn   = (u16*)alloc((size_t)MTOK * D_MODEL * 2);  // A
  u16* qb   = (u16*)alloc((size_t)MTOK * D_MODEL * 2);  // B: reused as hn
  u16* kb   = (u16*)alloc((size_t)MTOK * D_MODEL * 2);  // C
  u16* vb   = (u16*)alloc((size_t)MTOK * D_MODEL * 2);  // D: used as ob (flash out)
  u16* x1   = (u16*)alloc((size_t)MTOK * HP2 * 2);      // E: vbt before W13, then x1
  u16* w13i = (u16*)alloc((size_t)11264 * D_MODEL * 2); // F: interleaved W1/W3 weights
  u16* wsl  = (u16*)alloc((size_t)3 * D_MODEL * D_MODEL * 2);  // G: shared weight slot
  u16* vbt = x1;  // [32 bh][128 d][2048 s] — dead until W13 overwrites
  u16* ob  = vb;
  u16* hn  = qb;

  // ---- attention sublayer ----
  k_rmsnorm<<<MTOK, 256, 0, stream>>>(x, ga, xn);
  k_conv3<<<1536, 256, 0, stream>>>(wq, wk, wv, wsl);
  // QKV fused (col-major XCD chunks); V written directly transposed into vbt
  k_gemm2<4, 1, 1><<<dim3(6144 / 256, MTOK / 256), 512, 0, stream>>>(
      xn, wsl, qb, kb, vbt, nullptr, nullptr, MTOK, 6144, D_MODEL);
  k_rope<<<1024, 256, 0, stream>>>(qb, kb, fc);
  dim3 gfl(SEQ / 128, BATCH * NHEADS);
  k_flash4<<<gfl, 256, 0, stream>>>(qb, kb, vbt, ob);
  k_conv8<<<1024, 256, 0, stream>>>(wo, wsl, D_MODEL * D_MODEL / 8);
  k_gemm2<2, 2, 0><<<dim3(2048 / 128, MTOK / 256), 512, 0, stream>>>(
      ob, wsl, out, nullptr, nullptr, bo, x, MTOK, D_MODEL, D_MODEL);

  // ---- FFN sublayer (hres lives in `out`) ----
  k_rmsnorm<<<MTOK, 256, 0, stream>>>(out, gf, hn);  // hn overwrites qb (dead)
  k_convffn<<<2048, 256, 0, stream>>>(w1, w3, w2, w13i, wsl);
  // W13 fused (col-major XCD chunks): reg-only silu(x1)*x3 -> x1
  k_gemm2<4, 6, 1><<<dim3(11264 / 256, MTOK / 256), 512, 0, stream>>>(
      hn, w13i, x1, nullptr, nullptr, nullptr, nullptr, MTOK, 11264, D_MODEL);
  k_gemm2<2, 3, 0><<<dim3(2048 / 128, MTOK / 256), 512, 0, stream>>>(
      x1, wsl, out, nullptr, nullptr, nullptr, out, MTOK, D_MODEL, HP2);
}